// Round 1
// baseline (1452.544 us; speedup 1.0000x reference)
//
#include <hip/hip_runtime.h>
#include <hip/hip_bf16.h>
#include <math.h>

#define ND 20000
#define NF 50000
#define NE 400000
// HID=128, H=8, D=16, L=2, IN=128, OUT=32

static __device__ __forceinline__ float gelu_f(float x) {
    return 0.5f * x * (1.0f + erff(x * 0.70710678118654752f));
}

// ---------------------------------------------------------------------------
// GEMM: Y[N,128] = out_act( in_act(X)[N,128] @ W[128,128] + bias )
// W row-major [k][c]. BM=128 rows per block, 256 threads, 8x8 per thread.
// ---------------------------------------------------------------------------
template<int IN_GELU, int OUT_RELU>
__global__ __launch_bounds__(256)
void gemm128(const float* __restrict__ X, const float* __restrict__ W,
             const float* __restrict__ bias, float* __restrict__ Y, int N) {
    __shared__ float Ws[128 * 128];   // [k][c]
    __shared__ float Xs[128 * 129];   // [row][k], pad to 129 to kill bank conflicts
    const int tid = threadIdx.x;
    const int row0 = blockIdx.x * 128;

    #pragma unroll 4
    for (int it = 0; it < 64; ++it) {
        int idx = it * 256 + tid;
        Ws[idx] = W[idx];
    }
    #pragma unroll 4
    for (int it = 0; it < 64; ++it) {
        int idx = it * 256 + tid;
        int r = idx >> 7, k = idx & 127;
        int gr = row0 + r;
        float v = (gr < N) ? X[gr * 128 + k] : 0.0f;
        if (IN_GELU) v = gelu_f(v);
        Xs[r * 129 + k] = v;
    }
    __syncthreads();

    const int tx = tid & 15, ty = tid >> 4;
    const int c0 = tx * 4, r0 = ty * 4;   // cols c0,c0+64 ; rows r0,r0+64 (4 each)
    float acc[8][8];
    #pragma unroll
    for (int i = 0; i < 8; ++i)
        #pragma unroll
        for (int j = 0; j < 8; ++j) acc[i][j] = 0.f;

    for (int k = 0; k < 128; ++k) {
        float a[8], b[8];
        #pragma unroll
        for (int i = 0; i < 4; ++i) {
            a[i]     = Xs[(r0 + i) * 129 + k];
            a[4 + i] = Xs[(r0 + 64 + i) * 129 + k];
        }
        *(float4*)&b[0] = *(float4*)&Ws[k * 128 + c0];
        *(float4*)&b[4] = *(float4*)&Ws[k * 128 + c0 + 64];
        #pragma unroll
        for (int i = 0; i < 8; ++i)
            #pragma unroll
            for (int j = 0; j < 8; ++j)
                acc[i][j] = fmaf(a[i], b[j], acc[i][j]);
    }

    #pragma unroll
    for (int ih = 0; ih < 2; ++ih)
        #pragma unroll
        for (int i = 0; i < 4; ++i) {
            int gr = row0 + ih * 64 + r0 + i;
            if (gr >= N) continue;
            #pragma unroll
            for (int jh = 0; jh < 2; ++jh) {
                float4 o;
                float* po = (float*)&o;
                #pragma unroll
                for (int j = 0; j < 4; ++j) {
                    float vv = acc[ih * 4 + i][jh * 4 + j] + bias[jh * 64 + c0 + j];
                    if (OUT_RELU) vv = fmaxf(vv, 0.f);
                    po[j] = vv;
                }
                *(float4*)&Y[gr * 128 + jh * 64 + c0] = o;
            }
        }
}

// ---------------------------------------------------------------------------
// Final head: Y[N,32] = X[N,128] @ W[128,32] + b
// ---------------------------------------------------------------------------
__global__ __launch_bounds__(256)
void gemm_out_k(const float* __restrict__ X, const float* __restrict__ W,
                const float* __restrict__ bias, float* __restrict__ Y, int N) {
    __shared__ float Ws[128 * 32];
    __shared__ float Xs[8][128];
    const int tid = threadIdx.x;
    const int row0 = blockIdx.x * 8;
    #pragma unroll
    for (int it = 0; it < 16; ++it) Ws[it * 256 + tid] = W[it * 256 + tid];
    #pragma unroll
    for (int it = 0; it < 4; ++it) {
        int idx = it * 256 + tid;
        int r = idx >> 7, k = idx & 127;
        int gr = row0 + r;
        Xs[r][k] = (gr < N) ? X[gr * 128 + k] : 0.f;
    }
    __syncthreads();
    const int r = tid >> 5, c = tid & 31;
    float acc = bias[c];
    #pragma unroll 8
    for (int k = 0; k < 128; ++k)
        acc = fmaf(Xs[r][k], Ws[k * 32 + c], acc);
    int gr = row0 + r;
    if (gr < N) Y[gr * 32 + c] = acc;
}

// ---------------------------------------------------------------------------
// Fold a_rel/m_rel (+ p_rel/sqrt(D) for k) into Wk/Wv and biases.
// WkF[lt][i][h*16+e] = sum_d Wk[lt][i][h*16+d]*a[lt][h][d][e] * (p[lt][h]/4)
// row index 128 encodes the bias row.
// ---------------------------------------------------------------------------
__global__ void fold_weights(const float* __restrict__ Wk, const float* __restrict__ Wv,
                             const float* __restrict__ bk, const float* __restrict__ bv,
                             const float* __restrict__ a_rel, const float* __restrict__ m_rel,
                             const float* __restrict__ p_rel,
                             float* __restrict__ WkF, float* __restrict__ WvF,
                             float* __restrict__ bkF, float* __restrict__ bvF) {
    int idx = blockIdx.x * 256 + threadIdx.x;
    if (idx >= 2 * 4 * 129 * 128) return;
    int c = idx & 127;
    int tmp = idx >> 7;
    int row = tmp % 129;
    int tmp2 = tmp / 129;
    int lt = tmp2 & 3;
    int which = tmp2 >> 2;          // 0 = k-side (a_rel), 1 = v-side (m_rel)
    int h = c >> 4, e = c & 15;
    const float* R = (which == 0 ? a_rel : m_rel) + (lt * 8 + h) * 256;
    float scale = (which == 0) ? p_rel[lt * 8 + h] * 0.25f : 1.0f;
    float accv = 0.f;
    if (row < 128) {
        const float* Wsrc = (which == 0 ? Wk : Wv) + lt * 16384 + row * 128 + h * 16;
        #pragma unroll
        for (int d = 0; d < 16; ++d) accv += Wsrc[d] * R[d * 16 + e];
        float* Wdst = (which == 0 ? WkF : WvF);
        Wdst[lt * 16384 + row * 128 + c] = accv * scale;
    } else {
        const float* bsrc = (which == 0 ? bk : bv) + lt * 128 + h * 16;
        #pragma unroll
        for (int d = 0; d < 16; ++d) accv += bsrc[d] * R[d * 16 + e];
        float* bdst = (which == 0 ? bkF : bvF);
        bdst[lt * 128 + c] = accv * scale;
    }
}

// ---------------------------------------------------------------------------
// Edge aggregation: one wave per dst node, online segment softmax.
// lane l: head h=l>>3, dims 2*l, 2*l+1 (== h*16 + (l&7)*2).
// ---------------------------------------------------------------------------
__global__ __launch_bounds__(256)
void edge_agg(const float* __restrict__ q, const float* __restrict__ kt,
              const float* __restrict__ vt, const int* __restrict__ row_start,
              const int* __restrict__ esrc, float* __restrict__ agg, int n_dst) {
    int dst = (blockIdx.x * 256 + threadIdx.x) >> 6;
    int lane = threadIdx.x & 63;
    if (dst >= n_dst) return;
    float2 qv = *(const float2*)&q[dst * 128 + lane * 2];
    int p0 = row_start[dst], p1 = row_start[dst + 1];
    float m = -INFINITY, s = 0.f, a0 = 0.f, a1 = 0.f;
    for (int p = p0; p < p1; ++p) {
        int src = esrc[p];
        float2 kv = *(const float2*)&kt[src * 128 + lane * 2];
        float2 vv = *(const float2*)&vt[src * 128 + lane * 2];
        float part = qv.x * kv.x + qv.y * kv.y;
        part += __shfl_xor(part, 1);
        part += __shfl_xor(part, 2);
        part += __shfl_xor(part, 4);   // full per-head dot (scale pre-folded)
        float mn = fmaxf(m, part);
        float fac = __expf(m - mn);    // m=-inf on first edge -> fac=0
        float w = __expf(part - mn);
        s = s * fac + w;
        a0 = a0 * fac + w * vv.x;
        a1 = a1 * fac + w * vv.y;
        m = mn;
    }
    float r = 1.0f / (s + 1e-16f);
    float2 outv = make_float2(a0 * r, a1 * r);
    *(float2*)&agg[dst * 128 + lane * 2] = outv;
}

// ---------------------------------------------------------------------------
// HGT skip + residual + LayerNorm, in place on x. One wave per node.
// t = x + sk*o + (1-sk)*x ; x = LN(t)*g + b
// ---------------------------------------------------------------------------
__global__ __launch_bounds__(256)
void ln_skip(float* __restrict__ x, const float* __restrict__ o,
             const float* __restrict__ skipv, const float* __restrict__ g,
             const float* __restrict__ bb, int N) {
    int wid = (blockIdx.x * 256 + threadIdx.x) >> 6;
    int lane = threadIdx.x & 63;
    if (wid >= N) return;
    float sk = 1.f / (1.f + __expf(-skipv[0]));
    float2 xv = *(const float2*)&x[wid * 128 + lane * 2];
    float2 ov = *(const float2*)&o[wid * 128 + lane * 2];
    float t0 = xv.x + sk * ov.x + (1.f - sk) * xv.x;
    float t1 = xv.y + sk * ov.y + (1.f - sk) * xv.y;
    float s = t0 + t1;
    #pragma unroll
    for (int msk = 1; msk < 64; msk <<= 1) s += __shfl_xor(s, msk);
    float mean = s * (1.0f / 128.0f);
    float d0 = t0 - mean, d1 = t1 - mean;
    float vs = d0 * d0 + d1 * d1;
    #pragma unroll
    for (int msk = 1; msk < 64; msk <<= 1) vs += __shfl_xor(vs, msk);
    float inv = rsqrtf(vs * (1.0f / 128.0f) + 1e-5f);
    float2 outv = make_float2(d0 * inv * g[lane * 2] + bb[lane * 2],
                              d1 * inv * g[lane * 2 + 1] + bb[lane * 2 + 1]);
    *(float2*)&x[wid * 128 + lane * 2] = outv;
}

// ---------------------------------------------------------------------------
// CSR build
// ---------------------------------------------------------------------------
__global__ void k_count(const int* __restrict__ dst, int* __restrict__ cnt, int n_e) {
    int i = blockIdx.x * 256 + threadIdx.x;
    if (i < n_e) atomicAdd(&cnt[dst[i]], 1);
}

__global__ void k_scan_partial(const int* __restrict__ cnt, int* __restrict__ part, int n) {
    __shared__ int sd[256];
    int t = threadIdx.x;
    int base = blockIdx.x * 1024 + t * 4;
    int s = 0;
    #pragma unroll
    for (int j = 0; j < 4; ++j) { int i = base + j; if (i < n) s += cnt[i]; }
    sd[t] = s; __syncthreads();
    for (int off = 128; off > 0; off >>= 1) {
        if (t < off) sd[t] += sd[t + off];
        __syncthreads();
    }
    if (t == 0) part[blockIdx.x] = sd[0];
}

__global__ void k_scan_small(int* part, int nb, int* row_start, int n) {
    if (threadIdx.x == 0 && blockIdx.x == 0) {
        int run = 0;
        for (int i = 0; i < nb; ++i) { int v = part[i]; part[i] = run; run += v; }
        row_start[n] = run;
    }
}

__global__ void k_scan_final(const int* __restrict__ cnt, const int* __restrict__ part,
                             int* __restrict__ row_start, int n) {
    __shared__ int sd[256];
    int t = threadIdx.x;
    int base = blockIdx.x * 1024 + t * 4;
    int v[4]; int s = 0;
    #pragma unroll
    for (int j = 0; j < 4; ++j) { int i = base + j; v[j] = (i < n) ? cnt[i] : 0; s += v[j]; }
    sd[t] = s; __syncthreads();
    for (int off = 1; off < 256; off <<= 1) {
        int add = (t >= off) ? sd[t - off] : 0;
        __syncthreads();
        sd[t] += add;
        __syncthreads();
    }
    int excl = part[blockIdx.x] + sd[t] - s;
    #pragma unroll
    for (int j = 0; j < 4; ++j) {
        int i = base + j;
        if (i < n) row_start[i] = excl;
        excl += v[j];
    }
}

__global__ void k_copy_int(const int* __restrict__ a, int* __restrict__ b, int n) {
    int i = blockIdx.x * 256 + threadIdx.x;
    if (i < n) b[i] = a[i];
}

__global__ void k_fill(const int* __restrict__ src, const int* __restrict__ dst,
                       int* __restrict__ cursor, int* __restrict__ esrc, int n_e) {
    int i = blockIdx.x * 256 + threadIdx.x;
    if (i < n_e) {
        int p = atomicAdd(&cursor[dst[i]], 1);
        esrc[p] = src[i];
    }
}

// ---------------------------------------------------------------------------
extern "C" void kernel_launch(void* const* d_in, const int* in_sizes, int n_in,
                              void* d_out, int out_size, void* d_ws, size_t ws_size,
                              hipStream_t stream) {
    const float* x_device = (const float*)d_in[0];
    const float* x_feature = (const float*)d_in[1];
    const int* e_df_src = (const int*)d_in[2];
    const int* e_df_dst = (const int*)d_in[3];
    const int* e_fd_src = (const int*)d_in[4];
    const int* e_fd_dst = (const int*)d_in[5];
    const float* W_dev_in = (const float*)d_in[6];
    const float* b_dev_in = (const float*)d_in[7];
    const float* W_feat_in = (const float*)d_in[8];
    const float* b_feat_in = (const float*)d_in[9];
    const float* Wk = (const float*)d_in[10];
    const float* bk = (const float*)d_in[11];
    const float* Wq = (const float*)d_in[12];
    const float* bq = (const float*)d_in[13];
    const float* Wv = (const float*)d_in[14];
    const float* bv = (const float*)d_in[15];
    const float* a_rel = (const float*)d_in[16];
    const float* m_rel = (const float*)d_in[17];
    const float* p_rel = (const float*)d_in[18];
    const float* Wa = (const float*)d_in[19];
    const float* ba = (const float*)d_in[20];
    const float* skip = (const float*)d_in[21];
    const float* ln_g = (const float*)d_in[22];
    const float* ln_b = (const float*)d_in[23];
    const float* W_out = (const float*)d_in[24];
    const float* b_out = (const float*)d_in[25];

    char* ws = (char*)d_ws;
    size_t off = 0;
    auto alloc = [&](size_t bytes) -> void* {
        void* p = ws + off;
        off = (off + bytes + 255) & ~(size_t)255;
        return p;
    };
    float* xd    = (float*)alloc((size_t)ND * 128 * 4);
    float* xf    = (float*)alloc((size_t)NF * 128 * 4);
    float* q_d   = (float*)alloc((size_t)ND * 128 * 4);   // reused as o_d
    float* kt_d  = (float*)alloc((size_t)ND * 128 * 4);
    float* vt_d  = (float*)alloc((size_t)ND * 128 * 4);
    float* q_f   = (float*)alloc((size_t)NF * 128 * 4);   // reused as o_f
    float* kt_f  = (float*)alloc((size_t)NF * 128 * 4);
    float* vt_f  = (float*)alloc((size_t)NF * 128 * 4);
    float* agg_d = (float*)alloc((size_t)ND * 128 * 4);
    float* agg_f = (float*)alloc((size_t)NF * 128 * 4);
    float* WkF   = (float*)alloc(4 * 16384 * 4);
    float* WvF   = (float*)alloc(4 * 16384 * 4);
    float* bkF   = (float*)alloc(4 * 128 * 4);
    float* bvF   = (float*)alloc(4 * 128 * 4);
    int* cnt_f   = (int*)alloc((size_t)NF * 4);
    int* rs_f    = (int*)alloc((size_t)(NF + 1) * 4);
    int* esrc_f  = (int*)alloc((size_t)NE * 4);
    int* part_f  = (int*)alloc(64 * 4);
    int* cnt_d   = (int*)alloc((size_t)ND * 4);
    int* rs_d    = (int*)alloc((size_t)(ND + 1) * 4);
    int* esrc_d  = (int*)alloc((size_t)NE * 4);
    int* part_d  = (int*)alloc(64 * 4);

    const int EB = (NE + 255) / 256;

    // ---- CSR for edge type 0 (device -> feature), grouped by feature dst
    hipMemsetAsync(cnt_f, 0, (size_t)NF * 4, stream);
    k_count<<<EB, 256, 0, stream>>>(e_df_dst, cnt_f, NE);
    int nbF = (NF + 1023) / 1024;
    k_scan_partial<<<nbF, 256, 0, stream>>>(cnt_f, part_f, NF);
    k_scan_small<<<1, 64, 0, stream>>>(part_f, nbF, rs_f, NF);
    k_scan_final<<<nbF, 256, 0, stream>>>(cnt_f, part_f, rs_f, NF);
    k_copy_int<<<(NF + 255) / 256, 256, 0, stream>>>(rs_f, cnt_f, NF);
    k_fill<<<EB, 256, 0, stream>>>(e_df_src, e_df_dst, cnt_f, esrc_f, NE);

    // ---- CSR for edge type 1 (feature -> device), grouped by device dst
    hipMemsetAsync(cnt_d, 0, (size_t)ND * 4, stream);
    k_count<<<EB, 256, 0, stream>>>(e_fd_dst, cnt_d, NE);
    int nbD = (ND + 1023) / 1024;
    k_scan_partial<<<nbD, 256, 0, stream>>>(cnt_d, part_d, ND);
    k_scan_small<<<1, 64, 0, stream>>>(part_d, nbD, rs_d, ND);
    k_scan_final<<<nbD, 256, 0, stream>>>(cnt_d, part_d, rs_d, ND);
    k_copy_int<<<(ND + 255) / 256, 256, 0, stream>>>(rs_d, cnt_d, ND);
    k_fill<<<EB, 256, 0, stream>>>(e_fd_src, e_fd_dst, cnt_d, esrc_d, NE);

    // ---- fold relation matrices into k/v weights
    fold_weights<<<(2 * 4 * 129 * 128 + 255) / 256, 256, 0, stream>>>(
        Wk, Wv, bk, bv, a_rel, m_rel, p_rel, WkF, WvF, bkF, bvF);

    const int GBD = (ND + 127) / 128, GBF = (NF + 127) / 128;

    // ---- input projections + relu
    gemm128<0, 1><<<GBD, 256, 0, stream>>>(x_device, W_dev_in, b_dev_in, xd, ND);
    gemm128<0, 1><<<GBF, 256, 0, stream>>>(x_feature, W_feat_in, b_feat_in, xf, NF);

    for (int l = 0; l < 2; ++l) {
        for (int t = 0; t < 2; ++t) {
            const float* x_t = t ? xf : xd;
            float* q_t  = t ? q_f : q_d;
            float* kt_t = t ? kt_f : kt_d;
            float* vt_t = t ? vt_f : vt_d;
            int n_t = t ? NF : ND;
            int gb  = t ? GBF : GBD;
            int lt = l * 2 + t;
            gemm128<0, 0><<<gb, 256, 0, stream>>>(x_t, Wq + lt * 16384, bq + lt * 128, q_t, n_t);
            gemm128<0, 0><<<gb, 256, 0, stream>>>(x_t, WkF + lt * 16384, bkF + lt * 128, kt_t, n_t);
            gemm128<0, 0><<<gb, 256, 0, stream>>>(x_t, WvF + lt * 16384, bvF + lt * 128, vt_t, n_t);
        }
        // edge type 0: device -> feature
        edge_agg<<<(NF + 3) / 4, 256, 0, stream>>>(q_f, kt_d, vt_d, rs_f, esrc_f, agg_f, NF);
        // edge type 1: feature -> device
        edge_agg<<<(ND + 3) / 4, 256, 0, stream>>>(q_d, kt_f, vt_f, rs_d, esrc_d, agg_d, ND);

        // o = gelu(agg) @ Wa + ba   (o reuses q buffers)
        gemm128<1, 0><<<GBD, 256, 0, stream>>>(agg_d, Wa + (l * 2 + 0) * 16384, ba + (l * 2 + 0) * 128, q_d, ND);
        gemm128<1, 0><<<GBF, 256, 0, stream>>>(agg_f, Wa + (l * 2 + 1) * 16384, ba + (l * 2 + 1) * 128, q_f, NF);

        ln_skip<<<(ND + 3) / 4, 256, 0, stream>>>(xd, q_d, skip + l * 2 + 0,
                                                  ln_g + (l * 2 + 0) * 128, ln_b + (l * 2 + 0) * 128, ND);
        ln_skip<<<(NF + 3) / 4, 256, 0, stream>>>(xf, q_f, skip + l * 2 + 1,
                                                  ln_g + (l * 2 + 1) * 128, ln_b + (l * 2 + 1) * 128, NF);
    }

    gemm_out_k<<<(ND + 7) / 8, 256, 0, stream>>>(xd, W_out, b_out, (float*)d_out, ND);
}

// Round 2
// 563.836 us; speedup vs baseline: 2.5762x; 2.5762x over previous
//
#include <hip/hip_runtime.h>
#include <math.h>

#define ND 20000
#define NF 50000
#define NE 400000
// HID=128, H=8, D=16, L=2, IN=128, OUT=32

typedef __attribute__((ext_vector_type(8))) short short8;
typedef __attribute__((ext_vector_type(4))) float f32x4;

static __device__ __forceinline__ unsigned short f2bf(float f) {
    unsigned u = __builtin_bit_cast(unsigned, f);
    u += 0x7FFF + ((u >> 16) & 1);          // round-to-nearest-even
    return (unsigned short)(u >> 16);
}
static __device__ __forceinline__ float bf2f(unsigned short h) {
    return __builtin_bit_cast(float, (unsigned)h << 16);
}
static __device__ __forceinline__ float gelu_f(float x) {
    return 0.5f * x * (1.0f + erff(x * 0.70710678118654752f));
}

// ---------------------------------------------------------------------------
// Weight prep: WT[id][c][k] (bf16, c-major = pre-transposed) for 18 matrices:
// id 0: W_dev_in, 1: W_feat_in, 2+lt: Wq, 6+lt: WkF (a_rel,p_rel/4 folded),
// 10+lt: WvF (m_rel folded), 14+lt: Wa.   lt = l*2+t, 4 values.
// ---------------------------------------------------------------------------
__global__ void prep_weights(const float* __restrict__ W_dev_in, const float* __restrict__ W_feat_in,
                             const float* __restrict__ Wq, const float* __restrict__ Wk,
                             const float* __restrict__ Wv, const float* __restrict__ Wa,
                             const float* __restrict__ a_rel, const float* __restrict__ m_rel,
                             const float* __restrict__ p_rel, unsigned short* __restrict__ WT) {
    int idx = blockIdx.x * 256 + threadIdx.x;
    if (idx >= 18 * 16384) return;
    int k = idx & 127, c = (idx >> 7) & 127, id = idx >> 14;
    float val;
    if (id == 0) val = W_dev_in[k * 128 + c];
    else if (id == 1) val = W_feat_in[k * 128 + c];
    else if (id < 6) val = Wq[(id - 2) * 16384 + k * 128 + c];
    else if (id < 10) {
        int lt = id - 6, h = c >> 4, e = c & 15;
        const float* A = a_rel + (lt * 8 + h) * 256;
        const float* Ws = Wk + lt * 16384 + k * 128 + h * 16;
        float s = 0.f;
        #pragma unroll
        for (int d = 0; d < 16; ++d) s += Ws[d] * A[d * 16 + e];
        val = s * p_rel[lt * 8 + h] * 0.25f;
    } else if (id < 14) {
        int lt = id - 10, h = c >> 4, e = c & 15;
        const float* A = m_rel + (lt * 8 + h) * 256;
        const float* Ws = Wv + lt * 16384 + k * 128 + h * 16;
        float s = 0.f;
        #pragma unroll
        for (int d = 0; d < 16; ++d) s += Ws[d] * A[d * 16 + e];
        val = s;
    } else val = Wa[(id - 14) * 16384 + k * 128 + c];
    WT[(size_t)id * 16384 + c * 128 + k] = f2bf(val);
}

// B_all[id][128] fp32 biases, same id scheme (k/v biases folded).
__global__ void prep_bias(const float* __restrict__ b_dev_in, const float* __restrict__ b_feat_in,
                          const float* __restrict__ bq, const float* __restrict__ bk,
                          const float* __restrict__ bv, const float* __restrict__ ba,
                          const float* __restrict__ a_rel, const float* __restrict__ m_rel,
                          const float* __restrict__ p_rel, float* __restrict__ B_all) {
    int idx = blockIdx.x * 256 + threadIdx.x;
    if (idx >= 18 * 128) return;
    int c = idx & 127, id = idx >> 7;
    float v;
    if (id == 0) v = b_dev_in[c];
    else if (id == 1) v = b_feat_in[c];
    else if (id < 6) v = bq[(id - 2) * 128 + c];
    else if (id < 10) {
        int lt = id - 6, h = c >> 4, e = c & 15;
        const float* A = a_rel + (lt * 8 + h) * 256;
        const float* bs = bk + lt * 128 + h * 16;
        float s = 0.f;
        #pragma unroll
        for (int d = 0; d < 16; ++d) s += bs[d] * A[d * 16 + e];
        v = s * p_rel[lt * 8 + h] * 0.25f;
    } else if (id < 14) {
        int lt = id - 10, h = c >> 4, e = c & 15;
        const float* A = m_rel + (lt * 8 + h) * 256;
        const float* bs = bv + lt * 128 + h * 16;
        float s = 0.f;
        #pragma unroll
        for (int d = 0; d < 16; ++d) s += bs[d] * A[d * 16 + e];
        v = s;
    } else v = ba[(id - 14) * 128 + c];
    B_all[idx] = v;
}

// ---------------------------------------------------------------------------
// MFMA GEMM: Y[N,128](bf16) = act(X[N,128] @ W + bias). K=128 fixed.
// Block: 256 thr = 4 waves, each wave 32 rows x 128 cols. No LDS, no barriers.
// A-frag: lane holds X[row0+(l&15)][(l>>4)*8 + kf*32 ..+7]
// B-frag from WT[c][k]: lane holds W[k][cf*16+(l&15)] for same 8 k.
// D: col = lane&15, row = (lane>>4)*4 + reg.
// grid.y selects weight matrix id (stride wstride/bstride/ystride).
// ---------------------------------------------------------------------------
template<int AF32, int RELU>
__global__ __launch_bounds__(256) void mfma_gemm(
    const void* __restrict__ Xv, const unsigned short* __restrict__ WT0,
    const float* __restrict__ bias0, unsigned short* __restrict__ Y0,
    int N, int wstride, int bstride, long long ystride) {
    const int lane = threadIdx.x & 63;
    const int wave = threadIdx.x >> 6;
    const int row_base = blockIdx.x * 128 + wave * 32;
    const unsigned short* WT = WT0 + (size_t)blockIdx.y * wstride;
    const float* bias = bias0 + (size_t)blockIdx.y * bstride;
    unsigned short* Yp = Y0 + (size_t)blockIdx.y * ystride;
    const int l15 = lane & 15, lg = lane >> 4;
    const int kbase = lg * 8;

    short8 a[2][4];
    #pragma unroll
    for (int mf = 0; mf < 2; ++mf) {
        int r = row_base + mf * 16 + l15;
        r = r < N ? r : N - 1;
        if (AF32) {
            const float* Xf = (const float*)Xv + (size_t)r * 128;
            #pragma unroll
            for (int kf = 0; kf < 4; ++kf) {
                float4 lo = *(const float4*)(Xf + kf * 32 + kbase);
                float4 hi = *(const float4*)(Xf + kf * 32 + kbase + 4);
                short8 t;
                t[0] = (short)f2bf(lo.x); t[1] = (short)f2bf(lo.y);
                t[2] = (short)f2bf(lo.z); t[3] = (short)f2bf(lo.w);
                t[4] = (short)f2bf(hi.x); t[5] = (short)f2bf(hi.y);
                t[6] = (short)f2bf(hi.z); t[7] = (short)f2bf(hi.w);
                a[mf][kf] = t;
            }
        } else {
            const unsigned short* Xb = (const unsigned short*)Xv + (size_t)r * 128;
            #pragma unroll
            for (int kf = 0; kf < 4; ++kf)
                a[mf][kf] = *(const short8*)(Xb + kf * 32 + kbase);
        }
    }

    f32x4 acc[2][8];
    #pragma unroll
    for (int mf = 0; mf < 2; ++mf)
        #pragma unroll
        for (int cf = 0; cf < 8; ++cf) acc[mf][cf] = (f32x4){0.f, 0.f, 0.f, 0.f};

    #pragma unroll
    for (int cf = 0; cf < 8; ++cf) {
        #pragma unroll
        for (int kf = 0; kf < 4; ++kf) {
            short8 b = *(const short8*)(WT + (size_t)(cf * 16 + l15) * 128 + kf * 32 + kbase);
            acc[0][cf] = __builtin_amdgcn_mfma_f32_16x16x32_bf16(a[0][kf], b, acc[0][cf], 0, 0, 0);
            acc[1][cf] = __builtin_amdgcn_mfma_f32_16x16x32_bf16(a[1][kf], b, acc[1][cf], 0, 0, 0);
        }
    }

    float bval[8];
    #pragma unroll
    for (int cf = 0; cf < 8; ++cf) bval[cf] = bias[cf * 16 + l15];

    #pragma unroll
    for (int mf = 0; mf < 2; ++mf)
        #pragma unroll
        for (int r = 0; r < 4; ++r) {
            int grow = row_base + mf * 16 + lg * 4 + r;
            if (grow >= N) continue;
            #pragma unroll
            for (int cf = 0; cf < 8; ++cf) {
                float v = acc[mf][cf][r] + bval[cf];
                if (RELU) v = fmaxf(v, 0.f);
                Yp[(size_t)grow * 128 + cf * 16 + l15] = f2bf(v);
            }
        }
}

// ---------------------------------------------------------------------------
// Final head: Y[N,32](f32) = X(bf16)[N,128] @ W[128,32] + b
// ---------------------------------------------------------------------------
__global__ __launch_bounds__(256) void gemm_out_k(
    const unsigned short* __restrict__ X, const float* __restrict__ W,
    const float* __restrict__ bias, float* __restrict__ Y, int N) {
    __shared__ float Ws[128 * 32];
    __shared__ float Xs[8][128];
    const int tid = threadIdx.x;
    const int row0 = blockIdx.x * 8;
    #pragma unroll
    for (int it = 0; it < 16; ++it) Ws[it * 256 + tid] = W[it * 256 + tid];
    #pragma unroll
    for (int it = 0; it < 2; ++it) {
        int idx = it * 256 + tid;            // 512 uints = 8 rows x 64 pairs
        int rr = idx >> 6, kp = idx & 63;
        int gr = row0 + rr;
        unsigned u = (gr < N) ? *(const unsigned*)(X + (size_t)gr * 128 + kp * 2) : 0u;
        Xs[rr][kp * 2]     = bf2f((unsigned short)(u & 0xFFFFu));
        Xs[rr][kp * 2 + 1] = bf2f((unsigned short)(u >> 16));
    }
    __syncthreads();
    const int rr = tid >> 5, c = tid & 31;
    float acc = bias[c];
    #pragma unroll 8
    for (int k = 0; k < 128; ++k)
        acc = fmaf(Xs[rr][k], Ws[k * 32 + c], acc);
    int gr = row0 + rr;
    if (gr < N) Y[(size_t)gr * 32 + c] = acc;
}

// ---------------------------------------------------------------------------
// Edge aggregation, bf16 in/out, gelu fused into the epilogue.
// One wave per dst node; lane l: head l>>3, dims 2l, 2l+1.
// ---------------------------------------------------------------------------
__global__ __launch_bounds__(256) void edge_agg(
    const unsigned short* __restrict__ q, const unsigned short* __restrict__ kt,
    const unsigned short* __restrict__ vt, const int* __restrict__ row_start,
    const int* __restrict__ esrc, unsigned short* __restrict__ agg, int n_dst) {
    int dst = (blockIdx.x * 256 + threadIdx.x) >> 6;
    int lane = threadIdx.x & 63;
    if (dst >= n_dst) return;
    unsigned qb = *(const unsigned*)(q + (size_t)dst * 128 + lane * 2);
    float q0 = __builtin_bit_cast(float, qb << 16);
    float q1 = __builtin_bit_cast(float, qb & 0xFFFF0000u);
    int p0 = row_start[dst], p1 = row_start[dst + 1];
    float m = -INFINITY, s = 0.f, a0 = 0.f, a1 = 0.f;
    for (int p = p0; p < p1; ++p) {
        int src = esrc[p];
        unsigned kb = *(const unsigned*)(kt + (size_t)src * 128 + lane * 2);
        unsigned vb = *(const unsigned*)(vt + (size_t)src * 128 + lane * 2);
        float part = q0 * __builtin_bit_cast(float, kb << 16)
                   + q1 * __builtin_bit_cast(float, kb & 0xFFFF0000u);
        part += __shfl_xor(part, 1);
        part += __shfl_xor(part, 2);
        part += __shfl_xor(part, 4);        // full per-head dot (scale pre-folded)
        float mn = fmaxf(m, part);
        float fac = __expf(m - mn);         // m=-inf on first edge -> fac=0
        float w = __expf(part - mn);
        s = s * fac + w;
        a0 = a0 * fac + w * __builtin_bit_cast(float, vb << 16);
        a1 = a1 * fac + w * __builtin_bit_cast(float, vb & 0xFFFF0000u);
        m = mn;
    }
    float r = 1.0f / (s + 1e-16f);
    unsigned short o0 = f2bf(gelu_f(a0 * r));
    unsigned short o1 = f2bf(gelu_f(a1 * r));
    *(unsigned*)(agg + (size_t)dst * 128 + lane * 2) = (unsigned)o0 | ((unsigned)o1 << 16);
}

// ---------------------------------------------------------------------------
// HGT skip + residual + LayerNorm, in place on bf16 x. One wave per node.
// ---------------------------------------------------------------------------
__global__ __launch_bounds__(256) void ln_skip(
    unsigned short* __restrict__ x, const unsigned short* __restrict__ o,
    const float* __restrict__ skipv, const float* __restrict__ g,
    const float* __restrict__ bb, int N) {
    int wid = (blockIdx.x * 256 + threadIdx.x) >> 6;
    int lane = threadIdx.x & 63;
    if (wid >= N) return;
    float sk = 1.f / (1.f + __expf(-skipv[0]));
    unsigned xb = *(const unsigned*)(x + (size_t)wid * 128 + lane * 2);
    unsigned ob = *(const unsigned*)(o + (size_t)wid * 128 + lane * 2);
    float x0 = __builtin_bit_cast(float, xb << 16);
    float x1 = __builtin_bit_cast(float, xb & 0xFFFF0000u);
    float o0 = __builtin_bit_cast(float, ob << 16);
    float o1 = __builtin_bit_cast(float, ob & 0xFFFF0000u);
    float t0 = x0 + sk * o0 + (1.f - sk) * x0;
    float t1 = x1 + sk * o1 + (1.f - sk) * x1;
    float s = t0 + t1;
    #pragma unroll
    for (int msk = 1; msk < 64; msk <<= 1) s += __shfl_xor(s, msk);
    float mean = s * (1.0f / 128.0f);
    float d0 = t0 - mean, d1 = t1 - mean;
    float vs = d0 * d0 + d1 * d1;
    #pragma unroll
    for (int msk = 1; msk < 64; msk <<= 1) vs += __shfl_xor(vs, msk);
    float inv = rsqrtf(vs * (1.0f / 128.0f) + 1e-5f);
    unsigned short r0 = f2bf(d0 * inv * g[lane * 2] + bb[lane * 2]);
    unsigned short r1 = f2bf(d1 * inv * g[lane * 2 + 1] + bb[lane * 2 + 1]);
    *(unsigned*)(x + (size_t)wid * 128 + lane * 2) = (unsigned)r0 | ((unsigned)r1 << 16);
}

// ---------------------------------------------------------------------------
// CSR build (unchanged from round 1)
// ---------------------------------------------------------------------------
__global__ void k_count(const int* __restrict__ dst, int* __restrict__ cnt, int n_e) {
    int i = blockIdx.x * 256 + threadIdx.x;
    if (i < n_e) atomicAdd(&cnt[dst[i]], 1);
}

__global__ void k_scan_partial(const int* __restrict__ cnt, int* __restrict__ part, int n) {
    __shared__ int sd[256];
    int t = threadIdx.x;
    int base = blockIdx.x * 1024 + t * 4;
    int s = 0;
    #pragma unroll
    for (int j = 0; j < 4; ++j) { int i = base + j; if (i < n) s += cnt[i]; }
    sd[t] = s; __syncthreads();
    for (int off = 128; off > 0; off >>= 1) {
        if (t < off) sd[t] += sd[t + off];
        __syncthreads();
    }
    if (t == 0) part[blockIdx.x] = sd[0];
}

__global__ void k_scan_small(int* part, int nb, int* row_start, int n) {
    if (threadIdx.x == 0 && blockIdx.x == 0) {
        int run = 0;
        for (int i = 0; i < nb; ++i) { int v = part[i]; part[i] = run; run += v; }
        row_start[n] = run;
    }
}

__global__ void k_scan_final(const int* __restrict__ cnt, const int* __restrict__ part,
                             int* __restrict__ row_start, int n) {
    __shared__ int sd[256];
    int t = threadIdx.x;
    int base = blockIdx.x * 1024 + t * 4;
    int v[4]; int s = 0;
    #pragma unroll
    for (int j = 0; j < 4; ++j) { int i = base + j; v[j] = (i < n) ? cnt[i] : 0; s += v[j]; }
    sd[t] = s; __syncthreads();
    for (int off = 1; off < 256; off <<= 1) {
        int add = (t >= off) ? sd[t - off] : 0;
        __syncthreads();
        sd[t] += add;
        __syncthreads();
    }
    int excl = part[blockIdx.x] + sd[t] - s;
    #pragma unroll
    for (int j = 0; j < 4; ++j) {
        int i = base + j;
        if (i < n) row_start[i] = excl;
        excl += v[j];
    }
}

__global__ void k_copy_int(const int* __restrict__ a, int* __restrict__ b, int n) {
    int i = blockIdx.x * 256 + threadIdx.x;
    if (i < n) b[i] = a[i];
}

__global__ void k_fill(const int* __restrict__ src, const int* __restrict__ dst,
                       int* __restrict__ cursor, int* __restrict__ esrc, int n_e) {
    int i = blockIdx.x * 256 + threadIdx.x;
    if (i < n_e) {
        int p = atomicAdd(&cursor[dst[i]], 1);
        esrc[p] = src[i];
    }
}

// ---------------------------------------------------------------------------
extern "C" void kernel_launch(void* const* d_in, const int* in_sizes, int n_in,
                              void* d_out, int out_size, void* d_ws, size_t ws_size,
                              hipStream_t stream) {
    const float* x_device = (const float*)d_in[0];
    const float* x_feature = (const float*)d_in[1];
    const int* e_df_src = (const int*)d_in[2];
    const int* e_df_dst = (const int*)d_in[3];
    const int* e_fd_src = (const int*)d_in[4];
    const int* e_fd_dst = (const int*)d_in[5];
    const float* W_dev_in = (const float*)d_in[6];
    const float* b_dev_in = (const float*)d_in[7];
    const float* W_feat_in = (const float*)d_in[8];
    const float* b_feat_in = (const float*)d_in[9];
    const float* Wk = (const float*)d_in[10];
    const float* bk = (const float*)d_in[11];
    const float* Wq = (const float*)d_in[12];
    const float* bq = (const float*)d_in[13];
    const float* Wv = (const float*)d_in[14];
    const float* bv = (const float*)d_in[15];
    const float* a_rel = (const float*)d_in[16];
    const float* m_rel = (const float*)d_in[17];
    const float* p_rel = (const float*)d_in[18];
    const float* Wa = (const float*)d_in[19];
    const float* ba = (const float*)d_in[20];
    const float* skip = (const float*)d_in[21];
    const float* ln_g = (const float*)d_in[22];
    const float* ln_b = (const float*)d_in[23];
    const float* W_out = (const float*)d_in[24];
    const float* b_out = (const float*)d_in[25];

    char* ws = (char*)d_ws;
    size_t off = 0;
    auto alloc = [&](size_t bytes) -> void* {
        void* p = ws + off;
        off = (off + bytes + 255) & ~(size_t)255;
        return p;
    };
    typedef unsigned short us;
    us* xd     = (us*)alloc((size_t)ND * 128 * 2);
    us* xf     = (us*)alloc((size_t)NF * 128 * 2);
    us* qkv_d  = (us*)alloc((size_t)3 * ND * 128 * 2);
    us* qkv_f  = (us*)alloc((size_t)3 * NF * 128 * 2);
    us* agg_d  = (us*)alloc((size_t)ND * 128 * 2);
    us* agg_f  = (us*)alloc((size_t)NF * 128 * 2);
    us* o_d    = (us*)alloc((size_t)ND * 128 * 2);
    us* o_f    = (us*)alloc((size_t)NF * 128 * 2);
    us* WT     = (us*)alloc((size_t)18 * 16384 * 2);
    float* B_all = (float*)alloc(18 * 128 * 4);
    int* cnt_f  = (int*)alloc((size_t)NF * 4);
    int* rs_f   = (int*)alloc((size_t)(NF + 1) * 4);
    int* esrc_f = (int*)alloc((size_t)NE * 4);
    int* part_f = (int*)alloc(64 * 4);
    int* cnt_d  = (int*)alloc((size_t)ND * 4);
    int* rs_d   = (int*)alloc((size_t)(ND + 1) * 4);
    int* esrc_d = (int*)alloc((size_t)NE * 4);
    int* part_d = (int*)alloc(64 * 4);

    const int EB = (NE + 255) / 256;

    // ---- CSR edge type 0 (device -> feature), grouped by feature dst
    hipMemsetAsync(cnt_f, 0, (size_t)NF * 4, stream);
    k_count<<<EB, 256, 0, stream>>>(e_df_dst, cnt_f, NE);
    int nbF = (NF + 1023) / 1024;
    k_scan_partial<<<nbF, 256, 0, stream>>>(cnt_f, part_f, NF);
    k_scan_small<<<1, 64, 0, stream>>>(part_f, nbF, rs_f, NF);
    k_scan_final<<<nbF, 256, 0, stream>>>(cnt_f, part_f, rs_f, NF);
    k_copy_int<<<(NF + 255) / 256, 256, 0, stream>>>(rs_f, cnt_f, NF);
    k_fill<<<EB, 256, 0, stream>>>(e_df_src, e_df_dst, cnt_f, esrc_f, NE);

    // ---- CSR edge type 1 (feature -> device), grouped by device dst
    hipMemsetAsync(cnt_d, 0, (size_t)ND * 4, stream);
    k_count<<<EB, 256, 0, stream>>>(e_fd_dst, cnt_d, NE);
    int nbD = (ND + 1023) / 1024;
    k_scan_partial<<<nbD, 256, 0, stream>>>(cnt_d, part_d, ND);
    k_scan_small<<<1, 64, 0, stream>>>(part_d, nbD, rs_d, ND);
    k_scan_final<<<nbD, 256, 0, stream>>>(cnt_d, part_d, rs_d, ND);
    k_copy_int<<<(ND + 255) / 256, 256, 0, stream>>>(rs_d, cnt_d, ND);
    k_fill<<<EB, 256, 0, stream>>>(e_fd_src, e_fd_dst, cnt_d, esrc_d, NE);

    // ---- weight/bias prep (transpose to [c][k] bf16, fold relations)
    prep_weights<<<(18 * 16384 + 255) / 256, 256, 0, stream>>>(
        W_dev_in, W_feat_in, Wq, Wk, Wv, Wa, a_rel, m_rel, p_rel, WT);
    prep_bias<<<(18 * 128 + 255) / 256, 256, 0, stream>>>(
        b_dev_in, b_feat_in, bq, bk, bv, ba, a_rel, m_rel, p_rel, B_all);

    const int GBD = (ND + 127) / 128, GBF = (NF + 127) / 128;

    // ---- input projections + relu (fp32 in, bf16 out)
    mfma_gemm<1, 1><<<dim3(GBD, 1), 256, 0, stream>>>(
        x_device, WT + 0 * 16384, B_all + 0 * 128, xd, ND, 0, 0, 0);
    mfma_gemm<1, 1><<<dim3(GBF, 1), 256, 0, stream>>>(
        x_feature, WT + 1 * 16384, B_all + 1 * 128, xf, NF, 0, 0, 0);

    for (int l = 0; l < 2; ++l) {
        for (int t = 0; t < 2; ++t) {
            int lt = l * 2 + t;
            const us* x_t = t ? xf : xd;
            us* qkv_t = t ? qkv_f : qkv_d;
            int n_t = t ? NF : ND;
            int gb = t ? GBF : GBD;
            // fused q/k/v: grid.y = 3, weight ids (2+lt, 6+lt, 10+lt) -> stride 4 ids
            mfma_gemm<0, 0><<<dim3(gb, 3), 256, 0, stream>>>(
                x_t, WT + (size_t)(2 + lt) * 16384, B_all + (2 + lt) * 128, qkv_t,
                n_t, 4 * 16384, 4 * 128, (long long)n_t * 128);
        }
        // edge type 0: device -> feature
        edge_agg<<<(NF + 3) / 4, 256, 0, stream>>>(
            qkv_f, qkv_d + (size_t)ND * 128, qkv_d + (size_t)2 * ND * 128,
            rs_f, esrc_f, agg_f, NF);
        // edge type 1: feature -> device
        edge_agg<<<(ND + 3) / 4, 256, 0, stream>>>(
            qkv_d, qkv_f + (size_t)NF * 128, qkv_f + (size_t)2 * NF * 128,
            rs_d, esrc_d, agg_d, ND);

        // o = agg(gelu'd) @ Wa + ba
        mfma_gemm<0, 0><<<dim3(GBD, 1), 256, 0, stream>>>(
            agg_d, WT + (size_t)(14 + l * 2 + 0) * 16384, B_all + (14 + l * 2 + 0) * 128,
            o_d, ND, 0, 0, 0);
        mfma_gemm<0, 0><<<dim3(GBF, 1), 256, 0, stream>>>(
            agg_f, WT + (size_t)(14 + l * 2 + 1) * 16384, B_all + (14 + l * 2 + 1) * 128,
            o_f, NF, 0, 0, 0);

        ln_skip<<<(ND + 3) / 4, 256, 0, stream>>>(
            xd, o_d, skip + l * 2 + 0, ln_g + (size_t)(l * 2 + 0) * 128,
            ln_b + (size_t)(l * 2 + 0) * 128, ND);
        ln_skip<<<(NF + 3) / 4, 256, 0, stream>>>(
            xf, o_f, skip + l * 2 + 1, ln_g + (size_t)(l * 2 + 1) * 128,
            ln_b + (size_t)(l * 2 + 1) * 128, NF);
    }

    gemm_out_k<<<(ND + 7) / 8, 256, 0, stream>>>(xd, W_out, b_out, (float*)d_out, ND);
}

// Round 3
// 427.194 us; speedup vs baseline: 3.4002x; 1.3199x over previous
//
#include <hip/hip_runtime.h>
#include <math.h>

#define ND 20000
#define NF 50000
#define NE 400000
#define NT (NF + ND)     // combined dst nodes (feature first, then device)
// HID=128, H=8, D=16, L=2, IN=128, OUT=32

typedef __attribute__((ext_vector_type(8))) short short8;
typedef __attribute__((ext_vector_type(4))) float f32x4;
typedef unsigned short us;

static __device__ __forceinline__ us f2bf(float f) {
    unsigned u = __builtin_bit_cast(unsigned, f);
    u += 0x7FFF + ((u >> 16) & 1);          // round-to-nearest-even
    return (us)(u >> 16);
}
static __device__ __forceinline__ float bf2f(us h) {
    return __builtin_bit_cast(float, (unsigned)h << 16);
}
static __device__ __forceinline__ float bflo(unsigned u) {
    return __builtin_bit_cast(float, u << 16);
}
static __device__ __forceinline__ float bfhi(unsigned u) {
    return __builtin_bit_cast(float, u & 0xFFFF0000u);
}
static __device__ __forceinline__ float gelu_f(float x) {
    return 0.5f * x * (1.0f + erff(x * 0.70710678118654752f));
}

// ---------------------------------------------------------------------------
// Weight+bias prep. WT[id][c][k] (bf16, pre-transposed), B_all[id][128] fp32.
// id 0: W_dev_in, 1: W_feat_in, 2+lt: Wq, 6+lt: WkF (a_rel & p_rel/4 folded),
// 10+lt: WvF (m_rel folded), 14+lt: Wa.   lt = l*2+t.
// ---------------------------------------------------------------------------
__global__ void prep_all(const float* __restrict__ W_dev_in, const float* __restrict__ W_feat_in,
                         const float* __restrict__ Wq, const float* __restrict__ Wk,
                         const float* __restrict__ Wv, const float* __restrict__ Wa,
                         const float* __restrict__ b_dev_in, const float* __restrict__ b_feat_in,
                         const float* __restrict__ bq, const float* __restrict__ bk,
                         const float* __restrict__ bv, const float* __restrict__ ba,
                         const float* __restrict__ a_rel, const float* __restrict__ m_rel,
                         const float* __restrict__ p_rel,
                         us* __restrict__ WT, float* __restrict__ B_all) {
    int idx = blockIdx.x * 256 + threadIdx.x;
    if (idx < 18 * 16384) {
        int k = idx & 127, c = (idx >> 7) & 127, id = idx >> 14;
        float val;
        if (id == 0) val = W_dev_in[k * 128 + c];
        else if (id == 1) val = W_feat_in[k * 128 + c];
        else if (id < 6) val = Wq[(id - 2) * 16384 + k * 128 + c];
        else if (id < 10) {
            int lt = id - 6, h = c >> 4, e = c & 15;
            const float* A = a_rel + (lt * 8 + h) * 256;
            const float* Ws = Wk + lt * 16384 + k * 128 + h * 16;
            float sm = 0.f;
            #pragma unroll
            for (int d = 0; d < 16; ++d) sm += Ws[d] * A[d * 16 + e];
            val = sm * p_rel[lt * 8 + h] * 0.25f;
        } else if (id < 14) {
            int lt = id - 10, h = c >> 4, e = c & 15;
            const float* A = m_rel + (lt * 8 + h) * 256;
            const float* Ws = Wv + lt * 16384 + k * 128 + h * 16;
            float sm = 0.f;
            #pragma unroll
            for (int d = 0; d < 16; ++d) sm += Ws[d] * A[d * 16 + e];
            val = sm;
        } else val = Wa[(id - 14) * 16384 + k * 128 + c];
        WT[(size_t)id * 16384 + c * 128 + k] = f2bf(val);
    } else {
        int j = idx - 18 * 16384;
        if (j >= 18 * 128) return;
        int c = j & 127, id = j >> 7;
        float v;
        if (id == 0) v = b_dev_in[c];
        else if (id == 1) v = b_feat_in[c];
        else if (id < 6) v = bq[(id - 2) * 128 + c];
        else if (id < 10) {
            int lt = id - 6, h = c >> 4, e = c & 15;
            const float* A = a_rel + (lt * 8 + h) * 256;
            const float* bs = bk + lt * 128 + h * 16;
            float sm = 0.f;
            #pragma unroll
            for (int d = 0; d < 16; ++d) sm += bs[d] * A[d * 16 + e];
            v = sm * p_rel[lt * 8 + h] * 0.25f;
        } else if (id < 14) {
            int lt = id - 10, h = c >> 4, e = c & 15;
            const float* A = m_rel + (lt * 8 + h) * 256;
            const float* bs = bv + lt * 128 + h * 16;
            float sm = 0.f;
            #pragma unroll
            for (int d = 0; d < 16; ++d) sm += bs[d] * A[d * 16 + e];
            v = sm;
        } else v = ba[(id - 14) * 128 + c];
        B_all[j] = v;
    }
}

// ---------------------------------------------------------------------------
// MFMA GEMM over BOTH node types in one dispatch. blockIdx.x < GB0 -> type 0
// (device), else type 1 (feature). blockIdx.y = output plane (q/k/v).
// Weight id = widbase + type + 4*blockIdx.y. Y plane stride = N*128.
// Per block: 4 waves x 32 rows, no LDS.
// ---------------------------------------------------------------------------
template<int AF32, int RELU>
__global__ __launch_bounds__(256) void mfma_gemm2(
    const void* __restrict__ X0, const void* __restrict__ X1,
    const us* __restrict__ WT0, const float* __restrict__ Ball,
    us* __restrict__ Y0, us* __restrict__ Y1,
    int N0, int N1, int GB0, int widbase) {
    const int type = (blockIdx.x >= (unsigned)GB0) ? 1 : 0;
    const int bx = blockIdx.x - (type ? GB0 : 0);
    const int N = type ? N1 : N0;
    const void* Xv = type ? X1 : X0;
    const int wid = widbase + type + 4 * blockIdx.y;
    const us* WT = WT0 + (size_t)wid * 16384;
    const float* bias = Ball + wid * 128;
    us* Yp = (type ? Y1 : Y0) + (size_t)blockIdx.y * N * 128;

    const int lane = threadIdx.x & 63;
    const int wave = threadIdx.x >> 6;
    const int row_base = bx * 128 + wave * 32;
    const int l15 = lane & 15, lg = lane >> 4;
    const int kbase = lg * 8;

    short8 a[2][4];
    #pragma unroll
    for (int mf = 0; mf < 2; ++mf) {
        int r = row_base + mf * 16 + l15;
        r = r < N ? r : N - 1;
        if (AF32) {
            const float* Xf = (const float*)Xv + (size_t)r * 128;
            #pragma unroll
            for (int kf = 0; kf < 4; ++kf) {
                float4 lo = *(const float4*)(Xf + kf * 32 + kbase);
                float4 hi = *(const float4*)(Xf + kf * 32 + kbase + 4);
                short8 t;
                t[0] = (short)f2bf(lo.x); t[1] = (short)f2bf(lo.y);
                t[2] = (short)f2bf(lo.z); t[3] = (short)f2bf(lo.w);
                t[4] = (short)f2bf(hi.x); t[5] = (short)f2bf(hi.y);
                t[6] = (short)f2bf(hi.z); t[7] = (short)f2bf(hi.w);
                a[mf][kf] = t;
            }
        } else {
            const us* Xb = (const us*)Xv + (size_t)r * 128;
            #pragma unroll
            for (int kf = 0; kf < 4; ++kf)
                a[mf][kf] = *(const short8*)(Xb + kf * 32 + kbase);
        }
    }

    f32x4 acc[2][8];
    #pragma unroll
    for (int mf = 0; mf < 2; ++mf)
        #pragma unroll
        for (int cf = 0; cf < 8; ++cf) acc[mf][cf] = (f32x4){0.f, 0.f, 0.f, 0.f};

    #pragma unroll
    for (int cf = 0; cf < 8; ++cf) {
        #pragma unroll
        for (int kf = 0; kf < 4; ++kf) {
            short8 b = *(const short8*)(WT + (size_t)(cf * 16 + l15) * 128 + kf * 32 + kbase);
            acc[0][cf] = __builtin_amdgcn_mfma_f32_16x16x32_bf16(a[0][kf], b, acc[0][cf], 0, 0, 0);
            acc[1][cf] = __builtin_amdgcn_mfma_f32_16x16x32_bf16(a[1][kf], b, acc[1][cf], 0, 0, 0);
        }
    }

    float bval[8];
    #pragma unroll
    for (int cf = 0; cf < 8; ++cf) bval[cf] = bias[cf * 16 + l15];

    #pragma unroll
    for (int mf = 0; mf < 2; ++mf)
        #pragma unroll
        for (int r = 0; r < 4; ++r) {
            int grow = row_base + mf * 16 + lg * 4 + r;
            if (grow >= N) continue;
            #pragma unroll
            for (int cf = 0; cf < 8; ++cf) {
                float v = acc[mf][cf][r] + bval[cf];
                if (RELU) v = fmaxf(v, 0.f);
                Yp[(size_t)grow * 128 + cf * 16 + l15] = f2bf(v);
            }
        }
}

// ---------------------------------------------------------------------------
// Final head: Y[N,32](f32) = X(bf16)[N,128] @ W[128,32] + b
// ---------------------------------------------------------------------------
__global__ __launch_bounds__(256) void gemm_out_k(
    const us* __restrict__ X, const float* __restrict__ W,
    const float* __restrict__ bias, float* __restrict__ Y, int N) {
    __shared__ float Ws[128 * 32];
    __shared__ float Xs[8][128];
    const int tid = threadIdx.x;
    const int row0 = blockIdx.x * 8;
    #pragma unroll
    for (int it = 0; it < 16; ++it) Ws[it * 256 + tid] = W[it * 256 + tid];
    #pragma unroll
    for (int it = 0; it < 2; ++it) {
        int idx = it * 256 + tid;
        int rr = idx >> 6, kp = idx & 63;
        int gr = row0 + rr;
        unsigned u = (gr < N) ? *(const unsigned*)(X + (size_t)gr * 128 + kp * 2) : 0u;
        Xs[rr][kp * 2]     = bflo(u);
        Xs[rr][kp * 2 + 1] = bfhi(u);
    }
    __syncthreads();
    const int rr = tid >> 5, c = tid & 31;
    float acc = bias[c];
    #pragma unroll 8
    for (int k = 0; k < 128; ++k)
        acc = fmaf(Xs[rr][k], Ws[k * 32 + c], acc);
    int gr = row0 + rr;
    if (gr < N) Y[(size_t)gr * 32 + c] = acc;
}

// ---------------------------------------------------------------------------
// Edge aggregation, BOTH edge types in one dispatch. 16 lanes per dst node
// (4 dsts/wave): lane li owns dims [li*8, li*8+8); head = li>>1; per-head dot
// needs only shfl_xor(.,1). k/v gathers software-pipelined one edge ahead.
// gelu fused into epilogue.
// ---------------------------------------------------------------------------
__global__ __launch_bounds__(256) void edge_agg2(
    const us* __restrict__ qf, const us* __restrict__ qd,
    const us* __restrict__ ktf, const us* __restrict__ ktd,
    const us* __restrict__ vtf, const us* __restrict__ vtd,
    const int* __restrict__ rs, const int* __restrict__ esrc,
    us* __restrict__ aggf, us* __restrict__ aggd) {
    int g = (blockIdx.x * 256 + threadIdx.x) >> 4;
    int li = threadIdx.x & 15;
    if (g >= NT) return;
    const us *q, *kt, *vt; us* agg; int dst;
    if (g < NF) { dst = g;      q = qf; kt = ktd; vt = vtd; agg = aggf; }
    else        { dst = g - NF; q = qd; kt = ktf; vt = vtf; agg = aggd; }

    uint4 qb = *(const uint4*)(q + (size_t)dst * 128 + li * 8);
    float qv[8];
    qv[0] = bflo(qb.x); qv[1] = bfhi(qb.x);
    qv[2] = bflo(qb.y); qv[3] = bfhi(qb.y);
    qv[4] = bflo(qb.z); qv[5] = bfhi(qb.z);
    qv[6] = bflo(qb.w); qv[7] = bfhi(qb.w);

    int p0 = rs[g], p1 = rs[g + 1];
    float m = -INFINITY, s = 0.f;
    float a[8];
    #pragma unroll
    for (int j = 0; j < 8; ++j) a[j] = 0.f;

    uint4 kb, vb;
    if (p0 < p1) {
        int s0 = esrc[p0];
        kb = *(const uint4*)(kt + (size_t)s0 * 128 + li * 8);
        vb = *(const uint4*)(vt + (size_t)s0 * 128 + li * 8);
    }
    for (int p = p0; p < p1; ++p) {
        uint4 kc = kb, vc = vb;
        if (p + 1 < p1) {
            int sn = esrc[p + 1];
            kb = *(const uint4*)(kt + (size_t)sn * 128 + li * 8);
            vb = *(const uint4*)(vt + (size_t)sn * 128 + li * 8);
        }
        float part = qv[0] * bflo(kc.x);
        part = fmaf(qv[1], bfhi(kc.x), part);
        part = fmaf(qv[2], bflo(kc.y), part);
        part = fmaf(qv[3], bfhi(kc.y), part);
        part = fmaf(qv[4], bflo(kc.z), part);
        part = fmaf(qv[5], bfhi(kc.z), part);
        part = fmaf(qv[6], bflo(kc.w), part);
        part = fmaf(qv[7], bfhi(kc.w), part);
        part += __shfl_xor(part, 1);            // full 16-dim head dot
        float mn = fmaxf(m, part);
        float fac = __expf(m - mn);             // m=-inf first edge -> fac=0
        float w = __expf(part - mn);
        s = s * fac + w;
        float vf[8];
        vf[0] = bflo(vc.x); vf[1] = bfhi(vc.x);
        vf[2] = bflo(vc.y); vf[3] = bfhi(vc.y);
        vf[4] = bflo(vc.z); vf[5] = bfhi(vc.z);
        vf[6] = bflo(vc.w); vf[7] = bfhi(vc.w);
        #pragma unroll
        for (int j = 0; j < 8; ++j) a[j] = fmaf(w, vf[j], a[j] * fac);
        m = mn;
    }
    float r = 1.0f / (s + 1e-16f);
    unsigned o[4];
    #pragma unroll
    for (int j = 0; j < 4; ++j) {
        us lo = f2bf(gelu_f(a[2 * j] * r));
        us hi = f2bf(gelu_f(a[2 * j + 1] * r));
        o[j] = (unsigned)lo | ((unsigned)hi << 16);
    }
    *(uint4*)(agg + (size_t)dst * 128 + li * 8) = make_uint4(o[0], o[1], o[2], o[3]);
}

// ---------------------------------------------------------------------------
// HGT skip + residual + LayerNorm, both node types in one dispatch.
// One wave per node, in place on bf16 x.
// ---------------------------------------------------------------------------
__global__ __launch_bounds__(256) void ln_skip2(
    us* __restrict__ xd, us* __restrict__ xf,
    const us* __restrict__ od, const us* __restrict__ of,
    const float* __restrict__ skipv, const float* __restrict__ g_all,
    const float* __restrict__ b_all, int l) {
    int wid = (blockIdx.x * 256 + threadIdx.x) >> 6;
    int lane = threadIdx.x & 63;
    if (wid >= NT) return;
    int type, node;
    if (wid < ND) { type = 0; node = wid; }
    else          { type = 1; node = wid - ND; }
    us* x = type ? xf : xd;
    const us* o = type ? of : od;
    int lt = l * 2 + type;
    const float* g = g_all + (size_t)lt * 128;
    const float* bb = b_all + (size_t)lt * 128;
    float sk = 1.f / (1.f + __expf(-skipv[lt]));

    unsigned xb = *(const unsigned*)(x + (size_t)node * 128 + lane * 2);
    unsigned ob = *(const unsigned*)(o + (size_t)node * 128 + lane * 2);
    float x0 = bflo(xb), x1 = bfhi(xb);
    float o0 = bflo(ob), o1 = bfhi(ob);
    float t0 = x0 + sk * o0 + (1.f - sk) * x0;
    float t1 = x1 + sk * o1 + (1.f - sk) * x1;
    float s = t0 + t1;
    #pragma unroll
    for (int msk = 1; msk < 64; msk <<= 1) s += __shfl_xor(s, msk);
    float mean = s * (1.0f / 128.0f);
    float d0 = t0 - mean, d1 = t1 - mean;
    float vs = d0 * d0 + d1 * d1;
    #pragma unroll
    for (int msk = 1; msk < 64; msk <<= 1) vs += __shfl_xor(vs, msk);
    float inv = rsqrtf(vs * (1.0f / 128.0f) + 1e-5f);
    us r0 = f2bf(d0 * inv * g[lane * 2] + bb[lane * 2]);
    us r1 = f2bf(d1 * inv * g[lane * 2 + 1] + bb[lane * 2 + 1]);
    *(unsigned*)(x + (size_t)node * 128 + lane * 2) = (unsigned)r0 | ((unsigned)r1 << 16);
}

// ---------------------------------------------------------------------------
// CSR build over the COMBINED dst space (feature dsts [0,NF), device [NF,NT)).
// ---------------------------------------------------------------------------
__global__ void k_count2(const int* __restrict__ dA, const int* __restrict__ dB,
                         int* __restrict__ cnt) {
    int i = blockIdx.x * 256 + threadIdx.x;
    if (i < NE) atomicAdd(&cnt[dA[i]], 1);
    else if (i < 2 * NE) atomicAdd(&cnt[NF + dB[i - NE]], 1);
}

__global__ void k_scan_partial(const int* __restrict__ cnt, int* __restrict__ part, int n) {
    __shared__ int sd[256];
    int t = threadIdx.x;
    int base = blockIdx.x * 1024 + t * 4;
    int s = 0;
    #pragma unroll
    for (int j = 0; j < 4; ++j) { int i = base + j; if (i < n) s += cnt[i]; }
    sd[t] = s; __syncthreads();
    for (int off = 128; off > 0; off >>= 1) {
        if (t < off) sd[t] += sd[t + off];
        __syncthreads();
    }
    if (t == 0) part[blockIdx.x] = sd[0];
}

__global__ void k_scan_small(int* part, int nb, int* row_start, int n) {
    if (threadIdx.x == 0 && blockIdx.x == 0) {
        int run = 0;
        for (int i = 0; i < nb; ++i) { int v = part[i]; part[i] = run; run += v; }
        row_start[n] = run;
    }
}

__global__ void k_scan_final(const int* __restrict__ cnt, const int* __restrict__ part,
                             int* __restrict__ row_start, int n) {
    __shared__ int sd[256];
    int t = threadIdx.x;
    int base = blockIdx.x * 1024 + t * 4;
    int v[4]; int s = 0;
    #pragma unroll
    for (int j = 0; j < 4; ++j) { int i = base + j; v[j] = (i < n) ? cnt[i] : 0; s += v[j]; }
    sd[t] = s; __syncthreads();
    for (int off = 1; off < 256; off <<= 1) {
        int add = (t >= off) ? sd[t - off] : 0;
        __syncthreads();
        sd[t] += add;
        __syncthreads();
    }
    int excl = part[blockIdx.x] + sd[t] - s;
    #pragma unroll
    for (int j = 0; j < 4; ++j) {
        int i = base + j;
        if (i < n) row_start[i] = excl;
        excl += v[j];
    }
}

__global__ void k_copy_int(const int* __restrict__ a, int* __restrict__ b, int n) {
    int i = blockIdx.x * 256 + threadIdx.x;
    if (i < n) b[i] = a[i];
}

__global__ void k_fill2(const int* __restrict__ sA, const int* __restrict__ dA,
                        const int* __restrict__ sB, const int* __restrict__ dB,
                        int* __restrict__ cursor, int* __restrict__ esrc) {
    int i = blockIdx.x * 256 + threadIdx.x;
    if (i < NE) {
        int p = atomicAdd(&cursor[dA[i]], 1);
        esrc[p] = sA[i];
    } else if (i < 2 * NE) {
        int j = i - NE;
        int p = atomicAdd(&cursor[NF + dB[j]], 1);
        esrc[p] = sB[j];
    }
}

// ---------------------------------------------------------------------------
extern "C" void kernel_launch(void* const* d_in, const int* in_sizes, int n_in,
                              void* d_out, int out_size, void* d_ws, size_t ws_size,
                              hipStream_t stream) {
    const float* x_device = (const float*)d_in[0];
    const float* x_feature = (const float*)d_in[1];
    const int* e_df_src = (const int*)d_in[2];
    const int* e_df_dst = (const int*)d_in[3];
    const int* e_fd_src = (const int*)d_in[4];
    const int* e_fd_dst = (const int*)d_in[5];
    const float* W_dev_in = (const float*)d_in[6];
    const float* b_dev_in = (const float*)d_in[7];
    const float* W_feat_in = (const float*)d_in[8];
    const float* b_feat_in = (const float*)d_in[9];
    const float* Wk = (const float*)d_in[10];
    const float* bk = (const float*)d_in[11];
    const float* Wq = (const float*)d_in[12];
    const float* bq = (const float*)d_in[13];
    const float* Wv = (const float*)d_in[14];
    const float* bv = (const float*)d_in[15];
    const float* a_rel = (const float*)d_in[16];
    const float* m_rel = (const float*)d_in[17];
    const float* p_rel = (const float*)d_in[18];
    const float* Wa = (const float*)d_in[19];
    const float* ba = (const float*)d_in[20];
    const float* skip = (const float*)d_in[21];
    const float* ln_g = (const float*)d_in[22];
    const float* ln_b = (const float*)d_in[23];
    const float* W_out = (const float*)d_in[24];
    const float* b_out = (const float*)d_in[25];

    char* ws = (char*)d_ws;
    size_t off = 0;
    auto alloc = [&](size_t bytes) -> void* {
        void* p = ws + off;
        off = (off + bytes + 255) & ~(size_t)255;
        return p;
    };
    us* xd     = (us*)alloc((size_t)ND * 128 * 2);
    us* xf     = (us*)alloc((size_t)NF * 128 * 2);
    us* qkv_d  = (us*)alloc((size_t)3 * ND * 128 * 2);
    us* qkv_f  = (us*)alloc((size_t)3 * NF * 128 * 2);
    us* agg_d  = (us*)alloc((size_t)ND * 128 * 2);
    us* agg_f  = (us*)alloc((size_t)NF * 128 * 2);
    us* o_d    = (us*)alloc((size_t)ND * 128 * 2);
    us* o_f    = (us*)alloc((size_t)NF * 128 * 2);
    us* WT     = (us*)alloc((size_t)18 * 16384 * 2);
    float* B_all = (float*)alloc(18 * 128 * 4);
    int* cnt    = (int*)alloc((size_t)NT * 4);
    int* rs     = (int*)alloc((size_t)(NT + 1) * 4);
    int* esrc   = (int*)alloc((size_t)2 * NE * 4);
    int* part   = (int*)alloc(128 * 4);

    // ---- combined CSR build (feature dsts 0..NF, device dsts NF..NT)
    hipMemsetAsync(cnt, 0, (size_t)NT * 4, stream);
    k_count2<<<(2 * NE + 255) / 256, 256, 0, stream>>>(e_df_dst, e_fd_dst, cnt);
    int nb = (NT + 1023) / 1024;
    k_scan_partial<<<nb, 256, 0, stream>>>(cnt, part, NT);
    k_scan_small<<<1, 64, 0, stream>>>(part, nb, rs, NT);
    k_scan_final<<<nb, 256, 0, stream>>>(cnt, part, rs, NT);
    k_copy_int<<<(NT + 255) / 256, 256, 0, stream>>>(rs, cnt, NT);
    k_fill2<<<(2 * NE + 255) / 256, 256, 0, stream>>>(e_df_src, e_df_dst,
                                                      e_fd_src, e_fd_dst, cnt, esrc);

    // ---- weight/bias prep
    prep_all<<<(18 * 16384 + 18 * 128 + 255) / 256, 256, 0, stream>>>(
        W_dev_in, W_feat_in, Wq, Wk, Wv, Wa,
        b_dev_in, b_feat_in, bq, bk, bv, ba,
        a_rel, m_rel, p_rel, WT, B_all);

    const int GBD = (ND + 127) / 128, GBF = (NF + 127) / 128;

    // ---- input projections + relu (fp32 in, bf16 out), both types fused
    mfma_gemm2<1, 1><<<dim3(GBD + GBF, 1), 256, 0, stream>>>(
        x_device, x_feature, WT, B_all, xd, xf, ND, NF, GBD, 0);

    for (int l = 0; l < 2; ++l) {
        // fused q/k/v for both types: ids q=2+lt, k=6+lt, v=10+lt
        mfma_gemm2<0, 0><<<dim3(GBD + GBF, 3), 256, 0, stream>>>(
            xd, xf, WT, B_all, qkv_d, qkv_f, ND, NF, GBD, 2 + l * 2);

        // both edge types in one dispatch
        edge_agg2<<<((NT + 15) / 16 * 16 * 16 + 255) / 256, 256, 0, stream>>>(
            qkv_f, qkv_d,
            qkv_f + (size_t)NF * 128, qkv_d + (size_t)ND * 128,
            qkv_f + (size_t)2 * NF * 128, qkv_d + (size_t)2 * ND * 128,
            rs, esrc, agg_f, agg_d);

        // o = gelu(agg) @ Wa + ba, both types
        mfma_gemm2<0, 0><<<dim3(GBD + GBF, 1), 256, 0, stream>>>(
            agg_d, agg_f, WT, B_all, o_d, o_f, ND, NF, GBD, 14 + l * 2);

        // skip + residual + LN, both types
        ln_skip2<<<(NT + 3) / 4, 256, 0, stream>>>(
            xd, xf, o_d, o_f, skip, ln_g, ln_b, l);
    }

    gemm_out_k<<<(ND + 7) / 8, 256, 0, stream>>>(xd, W_out, b_out, (float*)d_out, ND);
}